// Round 20
// baseline (243.479 us; speedup 1.0000x reference)
//
#include <hip/hip_runtime.h>

// Problem constants
constexpr int NTOK = 16384;   // 8*2048 tokens
constexpr int KCB  = 8192;    // codebook size
constexpr int DDIM = 128;     // dim
constexpr int OUT_MAIN = NTOK * DDIM;   // 2097152

typedef _Float16 f16x8 __attribute__((ext_vector_type(8)));
typedef _Float16 f16x2 __attribute__((ext_vector_type(2)));
typedef float    f32x4 __attribute__((ext_vector_type(4)));

// Raw MFMA scores are cos*4096 (hi-only, x64*x64 scale).
// logits-in-log2 = raw * S12 where:
constexpr float S12 = 0.0035222047f;   // 10*log2(e) / 4096
// Schraudolph exp2: exp2(x) ~ bitcast(int(2^23*x + B)), B = 127*2^23 - 486411.
// Folded for raw scores: exp2(raw*S12) ~ bitcast(int(fma(raw, A12, SCHRB)))
constexpr float A12   = 29546.39f;       // S12 * 2^23
constexpr float SCHRB = 1064866805.0f;   // 127*2^23 - 486411
// Rescue threshold 1e-3 cos (20 sigma of hi-only rms error) in RAW units:
constexpr float RTHR_RAW = 4.096f;       // 1e-3 * 4096

__device__ __forceinline__ float fexp2raw(float raw) {
  return __int_as_float((int)fmaf(raw, A12, SCHRB));
}

// ---------------------------------------------------------------------------
// normalize rows of z and codebook; emit f16 hi (scaled x64) + 1/norm
// ---------------------------------------------------------------------------
__global__ __launch_bounds__(256) void norm_k(const float* __restrict__ z,
                                              const float* __restrict__ cb,
                                              _Float16* __restrict__ znh,
                                              _Float16* __restrict__ enh,
                                              float* __restrict__ zin,
                                              float* __restrict__ ein) {
  int lane = threadIdx.x & 63;
  int w    = threadIdx.x >> 6;
  int row  = blockIdx.x * 4 + w;
  const float* src;
  _Float16* dh;
  float* nv;
  if (row < NTOK) {
    src = z + (size_t)row * DDIM;
    dh = znh + (size_t)row * DDIM;
    nv = zin + row;
  } else {
    int r = row - NTOK;
    src = cb + (size_t)r * DDIM;
    dh = enh + (size_t)r * DDIM;
    nv = ein + r;
  }
  float2 v = reinterpret_cast<const float2*>(src)[lane];
  float ss = v.x * v.x + v.y * v.y;
#pragma unroll
  for (int m = 1; m < 64; m <<= 1) ss += __shfl_xor(ss, m);
  float rn = 1.0f / fmaxf(sqrtf(ss), 1e-12f);
  if (lane == 0) *nv = rn;
  float rs = rn * 64.0f;
  f16x2 h2;
  h2.x = (_Float16)(v.x * rs);
  h2.y = (_Float16)(v.y * rs);
  reinterpret_cast<f16x2*>(dh)[lane] = h2;
}

// ---------------------------------------------------------------------------
// transpose codebook: cbT[d][k] = cb[k][d]  (LDS-tiled, coalesced both sides)
// ---------------------------------------------------------------------------
__global__ __launch_bounds__(256) void transp_k(const float* __restrict__ cb,
                                                float* __restrict__ cbT) {
  __shared__ float t[32][65];
  int tid = threadIdx.x;
  int k0 = blockIdx.x * 64, d0 = blockIdx.y * 32;
#pragma unroll
  for (int p = 0; p < 8; ++p) {
    int idx = p * 256 + tid;
    int r = idx >> 5, c = idx & 31;
    t[c][r] = cb[(size_t)(k0 + r) * DDIM + d0 + c];
  }
  __syncthreads();
#pragma unroll
  for (int p = 0; p < 8; ++p) {
    int idx = p * 256 + tid;
    int c = idx >> 6, r = idx & 63;
    cbT[(size_t)(d0 + c) * KCB + k0 + r] = t[c][r];
  }
}

// ---------------------------------------------------------------------------
// pass1m: HI-ONLY MFMA argmax + Schraudolph exp2 sums.  grid (32, 32).
// (256,3): measured occupancy optimum (2w=86us, 3w=82us, 4w=spill/97us).
// R20: accumulator DOUBLE-BUFFER — issue next tile's MFMAs into the other
// acc set before the current epilogue, so the epilogue never waits on the
// MFMAs issued in the same step. x2-unrolled loop, named A/B sets.
// ---------------------------------------------------------------------------
__global__ __launch_bounds__(256, 3) void pass1m(const _Float16* __restrict__ znh,
                                                 const _Float16* __restrict__ enh,
                                                 float* __restrict__ pb1,
                                                 int* __restrict__ pidx,
                                                 float* __restrict__ pb2,
                                                 float* __restrict__ pL) {
  __shared__ float4 mbuf[32][4][16];   // 32 KB: [rt][wave][row]
  int tid = threadIdx.x, w = tid >> 6, l = tid & 63;
  int q = l >> 4, lr = l & 15;
  int part = blockIdx.x;               // 0..31
  int c0 = part * 256 + w * 64;
  int r0 = blockIdx.y * 512;           // 32 rowparts

  f16x8 bh[4][4];                      // codebook frags: [coltile][kchunk]
#pragma unroll
  for (int tt = 0; tt < 4; ++tt)
#pragma unroll
    for (int dc = 0; dc < 4; ++dc) {
      int col = c0 + tt * 16 + lr;
      bh[tt][dc] = *reinterpret_cast<const f16x8*>(enh + (size_t)col * DDIM + dc * 32 + q * 8);
    }

  // per-lane z pointer; advance by 16 rows (4096 B) per tile.
  // Over-reads up to 2 tiles (8KB) past the rowpart on the last iterations:
  // lands inside ws (znh is followed by scratch regions) and is discarded.
  const char* zp = reinterpret_cast<const char*>(
      znh + (size_t)(r0 + lr) * DDIM + q * 8);

  auto loadz = [&](f16x8 (&zz)[4]) {
#pragma unroll
    for (int dc = 0; dc < 4; ++dc)
      zz[dc] = *reinterpret_cast<const f16x8*>(zp + dc * 64);
    zp += 4096;
  };
  auto domfma = [&](f32x4 (&hh)[4], const f16x8 (&zz)[4]) {
#pragma unroll
    for (int tt = 0; tt < 4; ++tt)
#pragma unroll
      for (int e = 0; e < 4; ++e) hh[tt][e] = 0.0f;
#pragma unroll
    for (int dc = 0; dc < 4; ++dc)
#pragma unroll
      for (int tt = 0; tt < 4; ++tt)
        hh[tt] = __builtin_amdgcn_mfma_f32_16x16x32_f16(bh[tt][dc], zz[dc], hh[tt], 0, 0, 0);
  };
  auto epilogue = [&](const f32x4 (&hh)[4], int rt) {
    // raw scores (scaling is order-preserving -> tree works on raw)
    float s[16];
#pragma unroll
    for (int tt = 0; tt < 4; ++tt)
#pragma unroll
      for (int rg = 0; rg < 4; ++rg)
        s[tt * 4 + rg] = hh[tt][rg];

    // tree top2/argmax over 16 (ascending k within & across groups)
    float g1[4], g2[4];
    int   gi[4];
#pragma unroll
    for (int g = 0; g < 4; ++g) {
      float a = s[g * 4];
      float b = -3e38f;
      int   ix = 0;
#pragma unroll
      for (int j = 1; j < 4; ++j) {
        float sv = s[g * 4 + j];
        b = fmaxf(b, fminf(sv, a));
        ix = (sv > a) ? j : ix;
        a = fmaxf(a, sv);
      }
      g1[g] = a; g2[g] = b; gi[g] = g * 4 + ix;
    }
    float h1a = fmaxf(g1[0], g1[1]);
    int   hia = (g1[1] > g1[0]) ? gi[1] : gi[0];
    float h2a = fmaxf(fminf(g1[0], g1[1]), fmaxf(g2[0], g2[1]));
    float h1b = fmaxf(g1[2], g1[3]);
    int   hib = (g1[3] > g1[2]) ? gi[3] : gi[2];
    float h2b = fmaxf(fminf(g1[2], g1[3]), fmaxf(g2[2], g2[3]));
    float m1 = fmaxf(h1a, h1b);
    int   ii = (h1b > h1a) ? hib : hia;
    float m2 = fmaxf(fminf(h1a, h1b), fmaxf(h2a, h2b));
    int kk = c0 + q * 4 + ((ii >> 2) << 4) + (ii & 3);

    // Schraudolph exp2 sum (true exp2 domain) — pure tree
    float ex[16];
#pragma unroll
    for (int i = 0; i < 16; ++i) ex[i] = fexp2raw(s[i]);
#pragma unroll
    for (int st = 1; st < 16; st <<= 1)
#pragma unroll
      for (int i = 0; i < 16; i += 2 * st) ex[i] += ex[i + st];
    float Lr = ex[0];

    // q-group merge (lanes sharing this z-row)
#pragma unroll
    for (int m = 16; m <= 32; m <<= 1) {
      float o1 = __shfl_xor(m1, m), o2 = __shfl_xor(m2, m), oL = __shfl_xor(Lr, m);
      int ok = __shfl_xor(kk, m);
      Lr += oL;
      m2 = fmaxf(fminf(m1, o1), fmaxf(m2, o2));
      if (o1 > m1 || (o1 == m1 && ok < kk)) kk = ok;
      m1 = fmaxf(m1, o1);
    }
    if (l < 16) mbuf[rt][w][l] = make_float4(m1, __int_as_float(kk), m2, Lr);
  };

  f16x8 zA[4], zB[4];
  f32x4 hhA[4], hhB[4];
  loadz(zA);             // tile 0
  domfma(hhA, zA);       // scores(rt=0) in flight
  loadz(zB);             // tile 1
#pragma unroll 1
  for (int it = 0; it < 16; ++it) {
    loadz(zA);                         // tile 2it+2 (prefetch)
    domfma(hhB, zB);                   // scores(rt=2it+1) in flight
    epilogue(hhA, 2 * it);             // consume rt=2it (issued long ago)
    loadz(zB);                         // tile 2it+3 (prefetch)
    if (it < 15) domfma(hhA, zA);      // scores(rt=2it+2) in flight
    epilogue(hhB, 2 * it + 1);         // consume rt=2it+1
  }

  __syncthreads();
  int base = part * NTOK + r0;
  for (int e = tid; e < 512; e += 256) {
    int rt = e >> 4, rr = e & 15;
    float4 a = mbuf[rt][0][rr];
    float B1 = a.x, B2 = a.z, LL = a.w;
    int BI = __float_as_int(a.y);
#pragma unroll
    for (int ww = 1; ww < 4; ++ww) {   // waves ascending = col blocks ascending
      float4 o = mbuf[rt][ww][rr];
      LL += o.w;
      B2 = fmaxf(fminf(B1, o.x), fmaxf(B2, o.z));
      if (o.x > B1) BI = __float_as_int(o.y);
      B1 = fmaxf(B1, o.x);
    }
    int n = base + rt * 16 + rr;
    pb1[n] = B1; pidx[n] = BI; pb2[n] = B2; pL[n] = LL;
  }
}

// ---------------------------------------------------------------------------
// merge 32 col-part partials -> lse (log2 of raw sum), idx, counts; flag ties
// pb1/pb2 are RAW-score scale; flag compare uses RTHR_RAW.
// ---------------------------------------------------------------------------
__global__ __launch_bounds__(256) void merge2_k(const float* __restrict__ pb1,
                                                const int* __restrict__ pidx,
                                                const float* __restrict__ pb2,
                                                const float* __restrict__ pL,
                                                float* __restrict__ lse,
                                                int* __restrict__ idxb,
                                                int* __restrict__ counts,
                                                int* __restrict__ rcount,
                                                int* __restrict__ rlist) {
  int n = blockIdx.x * 256 + threadIdx.x;
  float B1 = pb1[n], B2 = pb2[n], LL = pL[n];
  int BI = pidx[n];
  for (int p = 1; p < 32; ++p) {
    int off = p * NTOK + n;
    float ob1 = pb1[off], ob2 = pb2[off], oL = pL[off];
    int oi = pidx[off];
    LL += oL;
    B2 = fmaxf(fminf(B1, ob1), fmaxf(B2, ob2));
    if (ob1 > B1) BI = oi;
    B1 = fmaxf(B1, ob1);
  }
  lse[n] = __log2f(LL);                // log2 of raw row-sum
  idxb[n] = BI;
  atomicAdd(&counts[BI], 1);
  if (B1 - B2 < RTHR_RAW) {
    int s = atomicAdd(rcount, 1);
    rlist[s] = n;
  }
}

// ---------------------------------------------------------------------------
// rescue2a: exact fp32 partial argmax. grid (256, 8): blockIdx.y = 1024-code
// chunk, blockIdx.x grid-strides over groups of 8 flagged rows. Writes
// per-(row,chunk) winner to rbufv/rbufi (no atomics, deterministic).
// ---------------------------------------------------------------------------
__global__ __launch_bounds__(256) void rescue2a_k(const float* __restrict__ z,
                                                  const float* __restrict__ cbT,
                                                  const float* __restrict__ zin,
                                                  const float* __restrict__ ein,
                                                  const int* __restrict__ rcount,
                                                  const int* __restrict__ rlist,
                                                  float* __restrict__ rbufv,
                                                  int* __restrict__ rbufi) {
  __shared__ float zr[8][DDIM];
  __shared__ float wbv[4][8];
  __shared__ int   wbi[4][8];
  int tid = threadIdx.x;
  int ch  = blockIdx.y;
  int cnt = *rcount;
  int ngrp = (cnt + 7) >> 3;
  for (int g = blockIdx.x; g < ngrp; g += gridDim.x) {
    int base = g * 8;
    int rows = min(8, cnt - base);
    __syncthreads();                   // protect zr/wbv reuse across groups
    int rr0 = tid >> 5, d4 = tid & 31;
    if (rr0 < rows) {
      int n = rlist[base + rr0];
      float rnz = zin[n];
      float4 v = reinterpret_cast<const float4*>(z + (size_t)n * DDIM)[d4];
      v.x *= rnz; v.y *= rnz; v.z *= rnz; v.w *= rnz;
      reinterpret_cast<float4*>(zr[rr0])[d4] = v;
    }
    __syncthreads();
    int c0 = ch * 1024 + tid * 4;
    float4 acc[8];
#pragma unroll
    for (int r = 0; r < 8; ++r) acc[r] = make_float4(0.f, 0.f, 0.f, 0.f);
#pragma unroll 2
    for (int d = 0; d < DDIM; ++d) {
      float4 e = reinterpret_cast<const float4*>(cbT + (size_t)d * KCB)[ch * 256 + tid];
#pragma unroll
      for (int r = 0; r < 8; ++r) {
        float zd = zr[r][d];
        acc[r].x = fmaf(e.x, zd, acc[r].x);
        acc[r].y = fmaf(e.y, zd, acc[r].y);
        acc[r].z = fmaf(e.z, zd, acc[r].z);
        acc[r].w = fmaf(e.w, zd, acc[r].w);
      }
    }
    float4 ev = reinterpret_cast<const float4*>(ein)[ch * 256 + tid];
    float bv[8];
    int   bi[8];
#pragma unroll
    for (int r = 0; r < 8; ++r) {
      float s0 = acc[r].x * ev.x, s1 = acc[r].y * ev.y;
      float s2 = acc[r].z * ev.z, s3 = acc[r].w * ev.w;
      float B = s0; int I = c0;                    // ascending c in thread
      if (s1 > B) { B = s1; I = c0 + 1; }
      if (s2 > B) { B = s2; I = c0 + 2; }
      if (s3 > B) { B = s3; I = c0 + 3; }
      bv[r] = B; bi[r] = I;
    }
#pragma unroll
    for (int m = 1; m < 64; m <<= 1) {
#pragma unroll
      for (int r = 0; r < 8; ++r) {
        float ov = __shfl_xor(bv[r], m);
        int   oi = __shfl_xor(bi[r], m);
        if (ov > bv[r] || (ov == bv[r] && oi < bi[r])) { bv[r] = ov; bi[r] = oi; }
      }
    }
    int wv = tid >> 6;
    if ((tid & 63) == 0) {
#pragma unroll
      for (int r = 0; r < 8; ++r) { wbv[wv][r] = bv[r]; wbi[wv][r] = bi[r]; }
    }
    __syncthreads();
    if (tid < rows) {
      int r = tid;
      float BV = wbv[0][r];
      int   BI = wbi[0][r];
#pragma unroll
      for (int ww = 1; ww < 4; ++ww)
        if (wbv[ww][r] > BV || (wbv[ww][r] == BV && wbi[ww][r] < BI)) {
          BV = wbv[ww][r]; BI = wbi[ww][r];
        }
      rbufv[(base + r) * 8 + ch] = BV;
      rbufi[(base + r) * 8 + ch] = BI;
    }
  }
}

// ---------------------------------------------------------------------------
// rescue2b: merge the 8 chunk winners per flagged row; fix idx + counts.
// ---------------------------------------------------------------------------
__global__ __launch_bounds__(256) void rescue2b_k(const int* __restrict__ rcount,
                                                  const int* __restrict__ rlist,
                                                  const float* __restrict__ rbufv,
                                                  const int* __restrict__ rbufi,
                                                  int* __restrict__ idxb,
                                                  int* __restrict__ counts) {
  int cnt = *rcount;
  for (int ri = blockIdx.x * 256 + threadIdx.x; ri < cnt; ri += gridDim.x * 256) {
    float BV = rbufv[ri * 8];
    int   BI = rbufi[ri * 8];
#pragma unroll
    for (int ch = 1; ch < 8; ++ch) {
      float v = rbufv[ri * 8 + ch];
      int   i = rbufi[ri * 8 + ch];
      if (v > BV) { BV = v; BI = i; }
    }
    int n = rlist[ri];
    int old = idxb[n];
    if (BI != old) {
      atomicSub(&counts[old], 1);
      atomicAdd(&counts[BI], 1);
      idxb[n] = BI;
    }
  }
}

// ---------------------------------------------------------------------------
// rescue (fallback, no cbT space); fixes counts
// ---------------------------------------------------------------------------
__global__ __launch_bounds__(256) void rescue_k(const float* __restrict__ z,
                                                const float* __restrict__ cb,
                                                const float* __restrict__ zin,
                                                const float* __restrict__ ein,
                                                const int* __restrict__ rcount,
                                                const int* __restrict__ rlist,
                                                int* __restrict__ idxb,
                                                int* __restrict__ counts) {
  __shared__ float rbv[4];
  __shared__ int   rbi[4];
  int tid = threadIdx.x, wv = tid >> 6, l = tid & 63;
  int half = l >> 5, ld = l & 31;
  int cnt = *rcount;
  for (int ri = blockIdx.x; ri < cnt; ri += gridDim.x) {
    int n = rlist[ri];
    __syncthreads();
    float rnz = zin[n];
    float4 zv = reinterpret_cast<const float4*>(z + (size_t)n * DDIM)[ld];
    zv.x *= rnz; zv.y *= rnz; zv.z *= rnz; zv.w *= rnz;
    float bv = -3e38f;
    int   bi = 0;
    for (int c0 = wv * 2; c0 < KCB; c0 += 8) {
      int c = c0 + half;
      float4 ev = reinterpret_cast<const float4*>(cb + (size_t)c * DDIM)[ld];
      float p = zv.x * ev.x;
      p = fmaf(zv.y, ev.y, p);
      p = fmaf(zv.z, ev.z, p);
      p = fmaf(zv.w, ev.w, p);
#pragma unroll
      for (int m = 1; m < 32; m <<= 1) p += __shfl_xor(p, m);
      float s = p * ein[c];
      if (s > bv) { bv = s; bi = c; }
    }
#pragma unroll
    for (int m = 1; m < 64; m <<= 1) {
      float ov = __shfl_xor(bv, m);
      int   oi = __shfl_xor(bi, m);
      if (ov > bv || (ov == bv && oi < bi)) { bv = ov; bi = oi; }
    }
    if (l == 0) { rbv[wv] = bv; rbi[wv] = bi; }
    __syncthreads();
    if (tid == 0) {
#pragma unroll
      for (int ww = 1; ww < 4; ++ww)
        if (rbv[ww] > bv || (rbv[ww] == bv && rbi[ww] < bi)) { bv = rbv[ww]; bi = rbi[ww]; }
      int old = idxb[n];
      if (bi != old) {
        atomicSub(&counts[old], 1);
        atomicAdd(&counts[bi], 1);
        idxb[n] = bi;
      }
    }
  }
}

// ---------------------------------------------------------------------------
// pass2r: register-resident softmax column sums; Schraudolph exp2 with the
// per-row lse folded into the bias. (256,4): working set ~100 regs < 128 cap.
// ---------------------------------------------------------------------------
__global__ __launch_bounds__(256, 4) void pass2r(const _Float16* __restrict__ znh,
                                                 const _Float16* __restrict__ enh,
                                                 const float* __restrict__ lse,
                                                 float* __restrict__ Ppart) {
  int tid = threadIdx.x, w = tid >> 6, l = tid & 63;
  int q = l >> 4, lr = l & 15;
  int part = blockIdx.x;
  int c0 = part * 256 + w * 64;
  int r0 = blockIdx.y * 512;

  f16x8 bh[4][4];
#pragma unroll
  for (int tt = 0; tt < 4; ++tt)
#pragma unroll
    for (int dc = 0; dc < 4; ++dc) {
      int col = c0 + tt * 16 + lr;
      bh[tt][dc] = *reinterpret_cast<const f16x8*>(enh + (size_t)col * DDIM + dc * 32 + q * 8);
    }

  f32x4 psum[4];
#pragma unroll
  for (int tt = 0; tt < 4; ++tt)
#pragma unroll
    for (int e = 0; e < 4; ++e) psum[tt][e] = 0.0f;

  const char* zp = reinterpret_cast<const char*>(
      znh + (size_t)(r0 + lr) * DDIM + q * 8);
  const float* lp = lse + r0 + lr;

  for (int rt = 0; rt < 32; ++rt) {
    f16x8 zh[4];
#pragma unroll
    for (int dc = 0; dc < 4; ++dc)
      zh[dc] = *reinterpret_cast<const f16x8*>(zp + dc * 64);
    zp += 4096;
    float lsez = lp[rt * 16];
    float bias = fmaf(lsez, -8388608.0f, SCHRB);   // fold -lse into Schraudolph
    f32x4 hh[4];
#pragma unroll
    for (int tt = 0; tt < 4; ++tt)
#pragma unroll
      for (int e = 0; e < 4; ++e) hh[tt][e] = 0.0f;
#pragma unroll
    for (int dc = 0; dc < 4; ++dc)
#pragma unroll
      for (int tt = 0; tt < 4; ++tt)
        hh[tt] = __builtin_amdgcn_mfma_f32_16x16x32_f16(bh[tt][dc], zh[dc], hh[tt], 0, 0, 0);
#pragma unroll
    for (int tt = 0; tt < 4; ++tt)
#pragma unroll
      for (int rg = 0; rg < 4; ++rg)
        psum[tt][rg] += __int_as_float((int)fmaf(hh[tt][rg], A12, bias));
  }

  // reduce over the 16 lr lanes (xor masks stay within the q-group)
#pragma unroll
  for (int m = 1; m < 16; m <<= 1)
#pragma unroll
    for (int tt = 0; tt < 4; ++tt)
#pragma unroll
      for (int rg = 0; rg < 4; ++rg)
        psum[tt][rg] += __shfl_xor(psum[tt][rg], m);

  if (lr == 0) {
    float* dst = Ppart + (size_t)blockIdx.y * KCB + c0;
#pragma unroll
    for (int tt = 0; tt < 4; ++tt)
#pragma unroll
      for (int rg = 0; rg < 4; ++rg)
        dst[tt * 16 + q * 4 + rg] = psum[tt][rg];
  }
}

// ---------------------------------------------------------------------------
// gather z_q, emit z_q_ste = z + (z_q - z), block-partial commit sums
// ---------------------------------------------------------------------------
__global__ __launch_bounds__(256) void k3(const float* __restrict__ z,
                                          const float* __restrict__ cb,
                                          const int* __restrict__ idxb,
                                          float* __restrict__ out,
                                          float* __restrict__ cpart) {
  int tid = threadIdx.x;
  int e   = blockIdx.x * 256 + tid;
  int n   = e >> 5;
  int q   = e & 31;
  int id  = idxb[n];
  float4 c4 = reinterpret_cast<const float4*>(cb)[id * 32 + q];
  float4 z4 = reinterpret_cast<const float4*>(z)[e];
  float4 o;
  o.x = z4.x + (c4.x - z4.x);
  o.y = z4.y + (c4.y - z4.y);
  o.z = z4.z + (c4.z - z4.z);
  o.w = z4.w + (c4.w - z4.w);
  reinterpret_cast<float4*>(out)[e] = o;
  float dx = c4.x - z4.x, dy = c4.y - z4.y, dz = c4.z - z4.z, dw = c4.w - z4.w;
  float ds = dx * dx + dy * dy + dz * dz + dw * dw;
#pragma unroll
  for (int m = 1; m < 64; m <<= 1) ds += __shfl_xor(ds, m);
  __shared__ float wsum[4];
  if ((tid & 63) == 0) wsum[tid >> 6] = ds;
  __syncthreads();
  if (tid == 0) cpart[blockIdx.x] = wsum[0] + wsum[1] + wsum[2] + wsum[3];
}

// ---------------------------------------------------------------------------
// reduce Ppart[rows][K] -> Psum[K]
// ---------------------------------------------------------------------------
__global__ __launch_bounds__(256) void reduceP(const float* __restrict__ Ppart,
                                               float* __restrict__ Psum,
                                               int rows) {
  int k = blockIdx.x * 256 + threadIdx.x;
  float s = 0.0f;
  for (int b = 0; b < rows; ++b) s += Ppart[(size_t)b * KCB + k];
  Psum[k] = s;
}

// ---------------------------------------------------------------------------
// final scalars: commit, perplexity, entropy_loss, min(ema)
// ---------------------------------------------------------------------------
__global__ __launch_bounds__(256) void finalk(const int* __restrict__ counts,
                                              const float* __restrict__ Psum,
                                              const float* __restrict__ pema,
                                              const float* __restrict__ cpart,
                                              float* __restrict__ out) {
  int tid = threadIdx.x;
  float s1 = 0.0f, s2 = 0.0f, cs = 0.0f, mn = 1e30f;
  const float invN = 1.0f / (float)NTOK;
  const float thr  = 0.0125f / (float)KCB;
  const float invK = 1.0f / (float)KCB;
  for (int k = tid; k < KCB; k += 256) {
    float e = (float)counts[k] * invN;
    s1 += e * logf(e + 1e-8f);
    float pa = Psum[k] * invN + 1e-8f;
    s2 += pa * logf(pa);
    float ema  = 0.9f * pema[k] + 0.1f * e;
    float emaf = (ema < thr) ? invK : ema;
    mn = fminf(mn, emaf);
  }
  for (int b = tid; b < 2048; b += 256) cs += cpart[b];
#pragma unroll
  for (int m = 1; m < 64; m <<= 1) {
    s1 += __shfl_xor(s1, m);
    s2 += __shfl_xor(s2, m);
    cs += __shfl_xor(cs, m);
    mn = fminf(mn, __shfl_xor(mn, m));
  }
  __shared__ float r1[4], r2[4], r3[4], r4[4];
  if ((tid & 63) == 0) {
    int w = tid >> 6;
    r1[w] = s1; r2[w] = s2; r3[w] = cs; r4[w] = mn;
  }
  __syncthreads();
  if (tid == 0) {
    float S1 = r1[0] + r1[1] + r1[2] + r1[3];
    float S2 = r2[0] + r2[1] + r2[2] + r2[3];
    float CS = r3[0] + r3[1] + r3[2] + r3[3];
    float MN = fminf(fminf(r4[0], r4[1]), fminf(r4[2], r4[3]));
    out[OUT_MAIN + 0] = 1.25f * CS / (float)OUT_MAIN;
    out[OUT_MAIN + 1] = expf(-S1);
    out[OUT_MAIN + 2] = -S2;
    out[OUT_MAIN + 3] = MN;
  }
}

// ---------------------------------------------------------------------------
extern "C" void kernel_launch(void* const* d_in, const int* in_sizes, int n_in,
                              void* d_out, int out_size, void* d_ws, size_t ws_size,
                              hipStream_t stream) {
  const float* z    = (const float*)d_in[0];
  const float* cb   = (const float*)d_in[1];
  const float* pema = (const float*)d_in[2];
  float* out = (float*)d_out;
  char*  ws  = (char*)d_ws;

  // workspace layout (25 MB with cbT)
  _Float16* znh = (_Float16*)(ws + 0x000000);            // 4 MB
  _Float16* enh = (_Float16*)(ws + 0x800000);            // 2 MB
  char* sb = ws + 0xC00000;
  float* zin    = (float*)(sb + 0x00000);                // 64 KB
  float* ein    = (float*)(sb + 0x10000);                // 32 KB
  float* lse    = (float*)(sb + 0x18000);                // 64 KB
  int*   idxb   = (int*)  (sb + 0x28000);                // 64 KB
  int*   counts = (int*)  (sb + 0x38000);                // 32 KB
  int*   rcount = (int*)  (sb + 0x40000);                // 4 B (+pad)
  int*   rlist  = (int*)  (sb + 0x41000);                // 64 KB
  float* Psum   = (float*)(sb + 0x51000);                // 32 KB
  float* cpart  = (float*)(sb + 0x59000);                // 8 KB
  char* pb = ws + 0xD00000;                              // partials: 8 MB
  float* pb1  = (float*)(pb + 0x000000);
  int*   pidx = (int*)  (pb + 0x200000);
  float* pb2  = (float*)(pb + 0x400000);
  float* pL   = (float*)(pb + 0x600000);
  // rescue partial buffers alias pb1/pidx space (dead after merge2_k):
  float* rbufv = (float*)(pb + 0x000000);                // 512 KB
  int*   rbufi = (int*)  (pb + 0x100000);                // 512 KB
  float* Ppart = (float*)(ws + 0x400000);                // 1 MB (lo slot, unused)
  float* cbT   = (float*)(ws + 0x1500000);               // 4 MB (optional)

  bool havecbt = ws_size >= (size_t)0x1900000;

  hipMemsetAsync(counts, 0, KCB * sizeof(int) + 0x400, stream);  // counts + rcount

  norm_k <<<(NTOK + KCB) / 4, 256, 0, stream>>>(z, cb, znh, enh, zin, ein);
  if (havecbt)
    transp_k<<<dim3(KCB / 64, DDIM / 32), 256, 0, stream>>>(cb, cbT);
  pass1m <<<dim3(32, 32),     256, 0, stream>>>(znh, enh, pb1, pidx, pb2, pL);
  merge2_k<<<NTOK / 256,      256, 0, stream>>>(pb1, pidx, pb2, pL, lse, idxb, counts, rcount, rlist);
  if (havecbt) {
    rescue2a_k<<<dim3(256, 8), 256, 0, stream>>>(z, cbT, zin, ein, rcount, rlist, rbufv, rbufi);
    rescue2b_k<<<64,           256, 0, stream>>>(rcount, rlist, rbufv, rbufi, idxb, counts);
  } else {
    rescue_k<<<1024,           256, 0, stream>>>(z, cb, zin, ein, rcount, rlist, idxb, counts);
  }
  pass2r <<<dim3(32, 32),     256, 0, stream>>>(znh, enh, lse, Ppart);
  k3     <<<NTOK * DDIM / 4 / 256, 256, 0, stream>>>(z, cb, idxb, out, cpart);
  reduceP<<<KCB / 256,        256, 0, stream>>>(Ppart, Psum, 32);
  finalk <<<1,                256, 0, stream>>>(counts, Psum, pema, cpart, out);
}

// Round 21
// 237.693 us; speedup vs baseline: 1.0243x; 1.0243x over previous
//
#include <hip/hip_runtime.h>

// Problem constants
constexpr int NTOK = 16384;   // 8*2048 tokens
constexpr int KCB  = 8192;    // codebook size
constexpr int DDIM = 128;     // dim
constexpr int OUT_MAIN = NTOK * DDIM;   // 2097152

typedef _Float16 f16x8 __attribute__((ext_vector_type(8)));
typedef _Float16 f16x2 __attribute__((ext_vector_type(2)));
typedef float    f32x4 __attribute__((ext_vector_type(4)));

// Raw MFMA scores are cos*4096 (hi-only, x64*x64 scale).
// logits-in-log2 = raw * S12 where:
constexpr float S12 = 0.0035222047f;   // 10*log2(e) / 4096
// Schraudolph exp2: exp2(x) ~ bitcast(int(2^23*x + B)), B = 127*2^23 - 486411.
// Folded for raw scores: exp2(raw*S12) ~ bitcast(int(fma(raw, A12, SCHRB)))
constexpr float A12   = 29546.39f;       // S12 * 2^23
constexpr float SCHRB = 1064866805.0f;   // 127*2^23 - 486411
// Rescue threshold 1e-3 cos (20 sigma of hi-only rms error) in RAW units:
constexpr float RTHR_RAW = 4.096f;       // 1e-3 * 4096

__device__ __forceinline__ float fexp2raw(float raw) {
  return __int_as_float((int)fmaf(raw, A12, SCHRB));
}

// ---------------------------------------------------------------------------
// normalize rows of z and codebook; emit f16 hi (scaled x64) + 1/norm
// ---------------------------------------------------------------------------
__global__ __launch_bounds__(256) void norm_k(const float* __restrict__ z,
                                              const float* __restrict__ cb,
                                              _Float16* __restrict__ znh,
                                              _Float16* __restrict__ enh,
                                              float* __restrict__ zin,
                                              float* __restrict__ ein) {
  int lane = threadIdx.x & 63;
  int w    = threadIdx.x >> 6;
  int row  = blockIdx.x * 4 + w;
  const float* src;
  _Float16* dh;
  float* nv;
  if (row < NTOK) {
    src = z + (size_t)row * DDIM;
    dh = znh + (size_t)row * DDIM;
    nv = zin + row;
  } else {
    int r = row - NTOK;
    src = cb + (size_t)r * DDIM;
    dh = enh + (size_t)r * DDIM;
    nv = ein + r;
  }
  float2 v = reinterpret_cast<const float2*>(src)[lane];
  float ss = v.x * v.x + v.y * v.y;
#pragma unroll
  for (int m = 1; m < 64; m <<= 1) ss += __shfl_xor(ss, m);
  float rn = 1.0f / fmaxf(sqrtf(ss), 1e-12f);
  if (lane == 0) *nv = rn;
  float rs = rn * 64.0f;
  f16x2 h2;
  h2.x = (_Float16)(v.x * rs);
  h2.y = (_Float16)(v.y * rs);
  reinterpret_cast<f16x2*>(dh)[lane] = h2;
}

// ---------------------------------------------------------------------------
// transpose codebook: cbT[d][k] = cb[k][d]  (LDS-tiled, coalesced both sides)
// ---------------------------------------------------------------------------
__global__ __launch_bounds__(256) void transp_k(const float* __restrict__ cb,
                                                float* __restrict__ cbT) {
  __shared__ float t[32][65];
  int tid = threadIdx.x;
  int k0 = blockIdx.x * 64, d0 = blockIdx.y * 32;
#pragma unroll
  for (int p = 0; p < 8; ++p) {
    int idx = p * 256 + tid;
    int r = idx >> 5, c = idx & 31;
    t[c][r] = cb[(size_t)(k0 + r) * DDIM + d0 + c];
  }
  __syncthreads();
#pragma unroll
  for (int p = 0; p < 8; ++p) {
    int idx = p * 256 + tid;
    int c = idx >> 6, r = idx & 63;
    cbT[(size_t)(d0 + c) * KCB + k0 + r] = t[c][r];
  }
}

// ---------------------------------------------------------------------------
// pass1m: HI-ONLY MFMA argmax (exact fp32 on raw scores) + Schraudolph exp2
// softmax sums.  grid (32, 32), 256 thr. Pointer-increment z addressing.
// (256,3): working set ~140 unified regs. Measured: 2 waves=86us, 3 waves=
// 82us, 4 waves=97us (spill), acc-dbuf=86us (occ 40->26%) -> this is optimal.
// ---------------------------------------------------------------------------
__global__ __launch_bounds__(256, 3) void pass1m(const _Float16* __restrict__ znh,
                                                 const _Float16* __restrict__ enh,
                                                 float* __restrict__ pb1,
                                                 int* __restrict__ pidx,
                                                 float* __restrict__ pb2,
                                                 float* __restrict__ pL) {
  __shared__ float4 mbuf[32][4][16];   // 32 KB: [rt][wave][row]
  int tid = threadIdx.x, w = tid >> 6, l = tid & 63;
  int q = l >> 4, lr = l & 15;
  int part = blockIdx.x;               // 0..31
  int c0 = part * 256 + w * 64;
  int r0 = blockIdx.y * 512;           // 32 rowparts

  f16x8 bh[4][4];                      // codebook frags: [coltile][kchunk]
#pragma unroll
  for (int tt = 0; tt < 4; ++tt)
#pragma unroll
    for (int dc = 0; dc < 4; ++dc) {
      int col = c0 + tt * 16 + lr;
      bh[tt][dc] = *reinterpret_cast<const f16x8*>(enh + (size_t)col * DDIM + dc * 32 + q * 8);
    }

  // per-lane z pointer; advance by 16 rows (4096 B) per rt
  const char* zp = reinterpret_cast<const char*>(
      znh + (size_t)(r0 + lr) * DDIM + q * 8);
  f16x8 zc[4];
#pragma unroll
  for (int dc = 0; dc < 4; ++dc)
    zc[dc] = *reinterpret_cast<const f16x8*>(zp + dc * 64);
  zp += 4096;

  for (int rt = 0; rt < 32; ++rt) {
    // prefetch next tile (last iter reads 4KB past rowpart: in-ws, discarded)
    f16x8 zn[4];
#pragma unroll
    for (int dc = 0; dc < 4; ++dc)
      zn[dc] = *reinterpret_cast<const f16x8*>(zp + dc * 64);
    zp += 4096;

    f32x4 hh[4];
#pragma unroll
    for (int tt = 0; tt < 4; ++tt)
#pragma unroll
      for (int e = 0; e < 4; ++e) hh[tt][e] = 0.0f;
#pragma unroll
    for (int dc = 0; dc < 4; ++dc)
#pragma unroll
      for (int tt = 0; tt < 4; ++tt)
        hh[tt] = __builtin_amdgcn_mfma_f32_16x16x32_f16(bh[tt][dc], zc[dc], hh[tt], 0, 0, 0);

    // raw scores (scaling is order-preserving -> tree works on raw)
    float s[16];
#pragma unroll
    for (int tt = 0; tt < 4; ++tt)
#pragma unroll
      for (int rg = 0; rg < 4; ++rg)
        s[tt * 4 + rg] = hh[tt][rg];

    // tree top2/argmax over 16 (ascending k within & across groups)
    float g1[4], g2[4];
    int   gi[4];
#pragma unroll
    for (int g = 0; g < 4; ++g) {
      float a = s[g * 4];
      float b = -3e38f;
      int   ix = 0;
#pragma unroll
      for (int j = 1; j < 4; ++j) {
        float sv = s[g * 4 + j];
        b = fmaxf(b, fminf(sv, a));
        ix = (sv > a) ? j : ix;
        a = fmaxf(a, sv);
      }
      g1[g] = a; g2[g] = b; gi[g] = g * 4 + ix;
    }
    float h1a = fmaxf(g1[0], g1[1]);
    int   hia = (g1[1] > g1[0]) ? gi[1] : gi[0];
    float h2a = fmaxf(fminf(g1[0], g1[1]), fmaxf(g2[0], g2[1]));
    float h1b = fmaxf(g1[2], g1[3]);
    int   hib = (g1[3] > g1[2]) ? gi[3] : gi[2];
    float h2b = fmaxf(fminf(g1[2], g1[3]), fmaxf(g2[2], g2[3]));
    float m1 = fmaxf(h1a, h1b);
    int   ii = (h1b > h1a) ? hib : hia;
    float m2 = fmaxf(fminf(h1a, h1b), fmaxf(h2a, h2b));
    int kk = c0 + q * 4 + ((ii >> 2) << 4) + (ii & 3);

    // Schraudolph exp2 sum (true exp2 domain) — pure tree
    float ex[16];
#pragma unroll
    for (int i = 0; i < 16; ++i) ex[i] = fexp2raw(s[i]);
#pragma unroll
    for (int st = 1; st < 16; st <<= 1)
#pragma unroll
      for (int i = 0; i < 16; i += 2 * st) ex[i] += ex[i + st];
    float Lr = ex[0];

    // q-group merge (lanes sharing this z-row)
#pragma unroll
    for (int m = 16; m <= 32; m <<= 1) {
      float o1 = __shfl_xor(m1, m), o2 = __shfl_xor(m2, m), oL = __shfl_xor(Lr, m);
      int ok = __shfl_xor(kk, m);
      Lr += oL;
      m2 = fmaxf(fminf(m1, o1), fmaxf(m2, o2));
      if (o1 > m1 || (o1 == m1 && ok < kk)) kk = ok;
      m1 = fmaxf(m1, o1);
    }
    if (l < 16) mbuf[rt][w][l] = make_float4(m1, __int_as_float(kk), m2, Lr);

#pragma unroll
    for (int dc = 0; dc < 4; ++dc) zc[dc] = zn[dc];
  }

  __syncthreads();
  int base = part * NTOK + r0;
  for (int e = tid; e < 512; e += 256) {
    int rt = e >> 4, rr = e & 15;
    float4 a = mbuf[rt][0][rr];
    float B1 = a.x, B2 = a.z, LL = a.w;
    int BI = __float_as_int(a.y);
#pragma unroll
    for (int ww = 1; ww < 4; ++ww) {   // waves ascending = col blocks ascending
      float4 o = mbuf[rt][ww][rr];
      LL += o.w;
      B2 = fmaxf(fminf(B1, o.x), fmaxf(B2, o.z));
      if (o.x > B1) BI = __float_as_int(o.y);
      B1 = fmaxf(B1, o.x);
    }
    int n = base + rt * 16 + rr;
    pb1[n] = B1; pidx[n] = BI; pb2[n] = B2; pL[n] = LL;
  }
}

// ---------------------------------------------------------------------------
// merge 32 col-part partials -> lse (log2 of raw sum), idx, counts; flag ties
// pb1/pb2 are RAW-score scale; flag compare uses RTHR_RAW.
// ---------------------------------------------------------------------------
__global__ __launch_bounds__(256) void merge2_k(const float* __restrict__ pb1,
                                                const int* __restrict__ pidx,
                                                const float* __restrict__ pb2,
                                                const float* __restrict__ pL,
                                                float* __restrict__ lse,
                                                int* __restrict__ idxb,
                                                int* __restrict__ counts,
                                                int* __restrict__ rcount,
                                                int* __restrict__ rlist) {
  int n = blockIdx.x * 256 + threadIdx.x;
  float B1 = pb1[n], B2 = pb2[n], LL = pL[n];
  int BI = pidx[n];
  for (int p = 1; p < 32; ++p) {
    int off = p * NTOK + n;
    float ob1 = pb1[off], ob2 = pb2[off], oL = pL[off];
    int oi = pidx[off];
    LL += oL;
    B2 = fmaxf(fminf(B1, ob1), fmaxf(B2, ob2));
    if (ob1 > B1) BI = oi;
    B1 = fmaxf(B1, ob1);
  }
  lse[n] = __log2f(LL);                // log2 of raw row-sum
  idxb[n] = BI;
  atomicAdd(&counts[BI], 1);
  if (B1 - B2 < RTHR_RAW) {
    int s = atomicAdd(rcount, 1);
    rlist[s] = n;
  }
}

// ---------------------------------------------------------------------------
// rescue2a: exact fp32 partial argmax. grid (256, 8): blockIdx.y = 1024-code
// chunk, blockIdx.x grid-strides over groups of 8 flagged rows. Writes
// per-(row,chunk) winner to rbufv/rbufi (no atomics, deterministic).
// ---------------------------------------------------------------------------
__global__ __launch_bounds__(256) void rescue2a_k(const float* __restrict__ z,
                                                  const float* __restrict__ cbT,
                                                  const float* __restrict__ zin,
                                                  const float* __restrict__ ein,
                                                  const int* __restrict__ rcount,
                                                  const int* __restrict__ rlist,
                                                  float* __restrict__ rbufv,
                                                  int* __restrict__ rbufi) {
  __shared__ float zr[8][DDIM];
  __shared__ float wbv[4][8];
  __shared__ int   wbi[4][8];
  int tid = threadIdx.x;
  int ch  = blockIdx.y;
  int cnt = *rcount;
  int ngrp = (cnt + 7) >> 3;
  for (int g = blockIdx.x; g < ngrp; g += gridDim.x) {
    int base = g * 8;
    int rows = min(8, cnt - base);
    __syncthreads();                   // protect zr/wbv reuse across groups
    int rr0 = tid >> 5, d4 = tid & 31;
    if (rr0 < rows) {
      int n = rlist[base + rr0];
      float rnz = zin[n];
      float4 v = reinterpret_cast<const float4*>(z + (size_t)n * DDIM)[d4];
      v.x *= rnz; v.y *= rnz; v.z *= rnz; v.w *= rnz;
      reinterpret_cast<float4*>(zr[rr0])[d4] = v;
    }
    __syncthreads();
    int c0 = ch * 1024 + tid * 4;
    float4 acc[8];
#pragma unroll
    for (int r = 0; r < 8; ++r) acc[r] = make_float4(0.f, 0.f, 0.f, 0.f);
#pragma unroll 2
    for (int d = 0; d < DDIM; ++d) {
      float4 e = reinterpret_cast<const float4*>(cbT + (size_t)d * KCB)[ch * 256 + tid];
#pragma unroll
      for (int r = 0; r < 8; ++r) {
        float zd = zr[r][d];
        acc[r].x = fmaf(e.x, zd, acc[r].x);
        acc[r].y = fmaf(e.y, zd, acc[r].y);
        acc[r].z = fmaf(e.z, zd, acc[r].z);
        acc[r].w = fmaf(e.w, zd, acc[r].w);
      }
    }
    float4 ev = reinterpret_cast<const float4*>(ein)[ch * 256 + tid];
    float bv[8];
    int   bi[8];
#pragma unroll
    for (int r = 0; r < 8; ++r) {
      float s0 = acc[r].x * ev.x, s1 = acc[r].y * ev.y;
      float s2 = acc[r].z * ev.z, s3 = acc[r].w * ev.w;
      float B = s0; int I = c0;                    // ascending c in thread
      if (s1 > B) { B = s1; I = c0 + 1; }
      if (s2 > B) { B = s2; I = c0 + 2; }
      if (s3 > B) { B = s3; I = c0 + 3; }
      bv[r] = B; bi[r] = I;
    }
#pragma unroll
    for (int m = 1; m < 64; m <<= 1) {
#pragma unroll
      for (int r = 0; r < 8; ++r) {
        float ov = __shfl_xor(bv[r], m);
        int   oi = __shfl_xor(bi[r], m);
        if (ov > bv[r] || (ov == bv[r] && oi < bi[r])) { bv[r] = ov; bi[r] = oi; }
      }
    }
    int wv = tid >> 6;
    if ((tid & 63) == 0) {
#pragma unroll
      for (int r = 0; r < 8; ++r) { wbv[wv][r] = bv[r]; wbi[wv][r] = bi[r]; }
    }
    __syncthreads();
    if (tid < rows) {
      int r = tid;
      float BV = wbv[0][r];
      int   BI = wbi[0][r];
#pragma unroll
      for (int ww = 1; ww < 4; ++ww)
        if (wbv[ww][r] > BV || (wbv[ww][r] == BV && wbi[ww][r] < BI)) {
          BV = wbv[ww][r]; BI = wbi[ww][r];
        }
      rbufv[(base + r) * 8 + ch] = BV;
      rbufi[(base + r) * 8 + ch] = BI;
    }
  }
}

// ---------------------------------------------------------------------------
// rescue2b: merge the 8 chunk winners per flagged row; fix idx + counts.
// ---------------------------------------------------------------------------
__global__ __launch_bounds__(256) void rescue2b_k(const int* __restrict__ rcount,
                                                  const int* __restrict__ rlist,
                                                  const float* __restrict__ rbufv,
                                                  const int* __restrict__ rbufi,
                                                  int* __restrict__ idxb,
                                                  int* __restrict__ counts) {
  int cnt = *rcount;
  for (int ri = blockIdx.x * 256 + threadIdx.x; ri < cnt; ri += gridDim.x * 256) {
    float BV = rbufv[ri * 8];
    int   BI = rbufi[ri * 8];
#pragma unroll
    for (int ch = 1; ch < 8; ++ch) {
      float v = rbufv[ri * 8 + ch];
      int   i = rbufi[ri * 8 + ch];
      if (v > BV) { BV = v; BI = i; }
    }
    int n = rlist[ri];
    int old = idxb[n];
    if (BI != old) {
      atomicSub(&counts[old], 1);
      atomicAdd(&counts[BI], 1);
      idxb[n] = BI;
    }
  }
}

// ---------------------------------------------------------------------------
// rescue (fallback, no cbT space); fixes counts
// ---------------------------------------------------------------------------
__global__ __launch_bounds__(256) void rescue_k(const float* __restrict__ z,
                                                const float* __restrict__ cb,
                                                const float* __restrict__ zin,
                                                const float* __restrict__ ein,
                                                const int* __restrict__ rcount,
                                                const int* __restrict__ rlist,
                                                int* __restrict__ idxb,
                                                int* __restrict__ counts) {
  __shared__ float rbv[4];
  __shared__ int   rbi[4];
  int tid = threadIdx.x, wv = tid >> 6, l = tid & 63;
  int half = l >> 5, ld = l & 31;
  int cnt = *rcount;
  for (int ri = blockIdx.x; ri < cnt; ri += gridDim.x) {
    int n = rlist[ri];
    __syncthreads();
    float rnz = zin[n];
    float4 zv = reinterpret_cast<const float4*>(z + (size_t)n * DDIM)[ld];
    zv.x *= rnz; zv.y *= rnz; zv.z *= rnz; zv.w *= rnz;
    float bv = -3e38f;
    int   bi = 0;
    for (int c0 = wv * 2; c0 < KCB; c0 += 8) {
      int c = c0 + half;
      float4 ev = reinterpret_cast<const float4*>(cb + (size_t)c * DDIM)[ld];
      float p = zv.x * ev.x;
      p = fmaf(zv.y, ev.y, p);
      p = fmaf(zv.z, ev.z, p);
      p = fmaf(zv.w, ev.w, p);
#pragma unroll
      for (int m = 1; m < 32; m <<= 1) p += __shfl_xor(p, m);
      float s = p * ein[c];
      if (s > bv) { bv = s; bi = c; }
    }
#pragma unroll
    for (int m = 1; m < 64; m <<= 1) {
      float ov = __shfl_xor(bv, m);
      int   oi = __shfl_xor(bi, m);
      if (ov > bv || (ov == bv && oi < bi)) { bv = ov; bi = oi; }
    }
    if (l == 0) { rbv[wv] = bv; rbi[wv] = bi; }
    __syncthreads();
    if (tid == 0) {
#pragma unroll
      for (int ww = 1; ww < 4; ++ww)
        if (rbv[ww] > bv || (rbv[ww] == bv && rbi[ww] < bi)) { bv = rbv[ww]; bi = rbi[ww]; }
      int old = idxb[n];
      if (bi != old) {
        atomicSub(&counts[old], 1);
        atomicAdd(&counts[bi], 1);
        idxb[n] = bi;
      }
    }
  }
}

// ---------------------------------------------------------------------------
// pass2r: register-resident softmax column sums; Schraudolph exp2 with the
// per-row lse folded into the bias. (256,4): working set ~100 regs < 128 cap.
// ---------------------------------------------------------------------------
__global__ __launch_bounds__(256, 4) void pass2r(const _Float16* __restrict__ znh,
                                                 const _Float16* __restrict__ enh,
                                                 const float* __restrict__ lse,
                                                 float* __restrict__ Ppart) {
  int tid = threadIdx.x, w = tid >> 6, l = tid & 63;
  int q = l >> 4, lr = l & 15;
  int part = blockIdx.x;
  int c0 = part * 256 + w * 64;
  int r0 = blockIdx.y * 512;

  f16x8 bh[4][4];
#pragma unroll
  for (int tt = 0; tt < 4; ++tt)
#pragma unroll
    for (int dc = 0; dc < 4; ++dc) {
      int col = c0 + tt * 16 + lr;
      bh[tt][dc] = *reinterpret_cast<const f16x8*>(enh + (size_t)col * DDIM + dc * 32 + q * 8);
    }

  f32x4 psum[4];
#pragma unroll
  for (int tt = 0; tt < 4; ++tt)
#pragma unroll
    for (int e = 0; e < 4; ++e) psum[tt][e] = 0.0f;

  const char* zp = reinterpret_cast<const char*>(
      znh + (size_t)(r0 + lr) * DDIM + q * 8);
  const float* lp = lse + r0 + lr;

  for (int rt = 0; rt < 32; ++rt) {
    f16x8 zh[4];
#pragma unroll
    for (int dc = 0; dc < 4; ++dc)
      zh[dc] = *reinterpret_cast<const f16x8*>(zp + dc * 64);
    zp += 4096;
    float lsez = lp[rt * 16];
    float bias = fmaf(lsez, -8388608.0f, SCHRB);   // fold -lse into Schraudolph
    f32x4 hh[4];
#pragma unroll
    for (int tt = 0; tt < 4; ++tt)
#pragma unroll
      for (int e = 0; e < 4; ++e) hh[tt][e] = 0.0f;
#pragma unroll
    for (int dc = 0; dc < 4; ++dc)
#pragma unroll
      for (int tt = 0; tt < 4; ++tt)
        hh[tt] = __builtin_amdgcn_mfma_f32_16x16x32_f16(bh[tt][dc], zh[dc], hh[tt], 0, 0, 0);
#pragma unroll
    for (int tt = 0; tt < 4; ++tt)
#pragma unroll
      for (int rg = 0; rg < 4; ++rg)
        psum[tt][rg] += __int_as_float((int)fmaf(hh[tt][rg], A12, bias));
  }

  // reduce over the 16 lr lanes (xor masks stay within the q-group)
#pragma unroll
  for (int m = 1; m < 16; m <<= 1)
#pragma unroll
    for (int tt = 0; tt < 4; ++tt)
#pragma unroll
      for (int rg = 0; rg < 4; ++rg)
        psum[tt][rg] += __shfl_xor(psum[tt][rg], m);

  if (lr == 0) {
    float* dst = Ppart + (size_t)blockIdx.y * KCB + c0;
#pragma unroll
    for (int tt = 0; tt < 4; ++tt)
#pragma unroll
      for (int rg = 0; rg < 4; ++rg)
        dst[tt * 16 + q * 4 + rg] = psum[tt][rg];
  }
}

// ---------------------------------------------------------------------------
// gather z_q, emit z_q_ste = z + (z_q - z), block-partial commit sums
// ---------------------------------------------------------------------------
__global__ __launch_bounds__(256) void k3(const float* __restrict__ z,
                                          const float* __restrict__ cb,
                                          const int* __restrict__ idxb,
                                          float* __restrict__ out,
                                          float* __restrict__ cpart) {
  int tid = threadIdx.x;
  int e   = blockIdx.x * 256 + tid;
  int n   = e >> 5;
  int q   = e & 31;
  int id  = idxb[n];
  float4 c4 = reinterpret_cast<const float4*>(cb)[id * 32 + q];
  float4 z4 = reinterpret_cast<const float4*>(z)[e];
  float4 o;
  o.x = z4.x + (c4.x - z4.x);
  o.y = z4.y + (c4.y - z4.y);
  o.z = z4.z + (c4.z - z4.z);
  o.w = z4.w + (c4.w - z4.w);
  reinterpret_cast<float4*>(out)[e] = o;
  float dx = c4.x - z4.x, dy = c4.y - z4.y, dz = c4.z - z4.z, dw = c4.w - z4.w;
  float ds = dx * dx + dy * dy + dz * dz + dw * dw;
#pragma unroll
  for (int m = 1; m < 64; m <<= 1) ds += __shfl_xor(ds, m);
  __shared__ float wsum[4];
  if ((tid & 63) == 0) wsum[tid >> 6] = ds;
  __syncthreads();
  if (tid == 0) cpart[blockIdx.x] = wsum[0] + wsum[1] + wsum[2] + wsum[3];
}

// ---------------------------------------------------------------------------
// reduce Ppart[rows][K] -> Psum[K]
// ---------------------------------------------------------------------------
__global__ __launch_bounds__(256) void reduceP(const float* __restrict__ Ppart,
                                               float* __restrict__ Psum,
                                               int rows) {
  int k = blockIdx.x * 256 + threadIdx.x;
  float s = 0.0f;
  for (int b = 0; b < rows; ++b) s += Ppart[(size_t)b * KCB + k];
  Psum[k] = s;
}

// ---------------------------------------------------------------------------
// final scalars: commit, perplexity, entropy_loss, min(ema)
// ---------------------------------------------------------------------------
__global__ __launch_bounds__(256) void finalk(const int* __restrict__ counts,
                                              const float* __restrict__ Psum,
                                              const float* __restrict__ pema,
                                              const float* __restrict__ cpart,
                                              float* __restrict__ out) {
  int tid = threadIdx.x;
  float s1 = 0.0f, s2 = 0.0f, cs = 0.0f, mn = 1e30f;
  const float invN = 1.0f / (float)NTOK;
  const float thr  = 0.0125f / (float)KCB;
  const float invK = 1.0f / (float)KCB;
  for (int k = tid; k < KCB; k += 256) {
    float e = (float)counts[k] * invN;
    s1 += e * logf(e + 1e-8f);
    float pa = Psum[k] * invN + 1e-8f;
    s2 += pa * logf(pa);
    float ema  = 0.9f * pema[k] + 0.1f * e;
    float emaf = (ema < thr) ? invK : ema;
    mn = fminf(mn, emaf);
  }
  for (int b = tid; b < 2048; b += 256) cs += cpart[b];
#pragma unroll
  for (int m = 1; m < 64; m <<= 1) {
    s1 += __shfl_xor(s1, m);
    s2 += __shfl_xor(s2, m);
    cs += __shfl_xor(cs, m);
    mn = fminf(mn, __shfl_xor(mn, m));
  }
  __shared__ float r1[4], r2[4], r3[4], r4[4];
  if ((tid & 63) == 0) {
    int w = tid >> 6;
    r1[w] = s1; r2[w] = s2; r3[w] = cs; r4[w] = mn;
  }
  __syncthreads();
  if (tid == 0) {
    float S1 = r1[0] + r1[1] + r1[2] + r1[3];
    float S2 = r2[0] + r2[1] + r2[2] + r2[3];
    float CS = r3[0] + r3[1] + r3[2] + r3[3];
    float MN = fminf(fminf(r4[0], r4[1]), fminf(r4[2], r4[3]));
    out[OUT_MAIN + 0] = 1.25f * CS / (float)OUT_MAIN;
    out[OUT_MAIN + 1] = expf(-S1);
    out[OUT_MAIN + 2] = -S2;
    out[OUT_MAIN + 3] = MN;
  }
}

// ---------------------------------------------------------------------------
extern "C" void kernel_launch(void* const* d_in, const int* in_sizes, int n_in,
                              void* d_out, int out_size, void* d_ws, size_t ws_size,
                              hipStream_t stream) {
  const float* z    = (const float*)d_in[0];
  const float* cb   = (const float*)d_in[1];
  const float* pema = (const float*)d_in[2];
  float* out = (float*)d_out;
  char*  ws  = (char*)d_ws;

  // workspace layout (25 MB with cbT)
  _Float16* znh = (_Float16*)(ws + 0x000000);            // 4 MB
  _Float16* enh = (_Float16*)(ws + 0x800000);            // 2 MB
  char* sb = ws + 0xC00000;
  float* zin    = (float*)(sb + 0x00000);                // 64 KB
  float* ein    = (float*)(sb + 0x10000);                // 32 KB
  float* lse    = (float*)(sb + 0x18000);                // 64 KB
  int*   idxb   = (int*)  (sb + 0x28000);                // 64 KB
  int*   counts = (int*)  (sb + 0x38000);                // 32 KB
  int*   rcount = (int*)  (sb + 0x40000);                // 4 B (+pad)
  int*   rlist  = (int*)  (sb + 0x41000);                // 64 KB
  float* Psum   = (float*)(sb + 0x51000);                // 32 KB
  float* cpart  = (float*)(sb + 0x59000);                // 8 KB
  char* pb = ws + 0xD00000;                              // partials: 8 MB
  float* pb1  = (float*)(pb + 0x000000);
  int*   pidx = (int*)  (pb + 0x200000);
  float* pb2  = (float*)(pb + 0x400000);
  float* pL   = (float*)(pb + 0x600000);
  // rescue partial buffers alias pb1/pidx space (dead after merge2_k):
  float* rbufv = (float*)(pb + 0x000000);                // 512 KB
  int*   rbufi = (int*)  (pb + 0x100000);                // 512 KB
  float* Ppart = (float*)(ws + 0x400000);                // 1 MB (lo slot, unused)
  float* cbT   = (float*)(ws + 0x1500000);               // 4 MB (optional)

  bool havecbt = ws_size >= (size_t)0x1900000;

  hipMemsetAsync(counts, 0, KCB * sizeof(int) + 0x400, stream);  // counts + rcount

  norm_k <<<(NTOK + KCB) / 4, 256, 0, stream>>>(z, cb, znh, enh, zin, ein);
  if (havecbt)
    transp_k<<<dim3(KCB / 64, DDIM / 32), 256, 0, stream>>>(cb, cbT);
  pass1m <<<dim3(32, 32),     256, 0, stream>>>(znh, enh, pb1, pidx, pb2, pL);
  merge2_k<<<NTOK / 256,      256, 0, stream>>>(pb1, pidx, pb2, pL, lse, idxb, counts, rcount, rlist);
  if (havecbt) {
    rescue2a_k<<<dim3(256, 8), 256, 0, stream>>>(z, cbT, zin, ein, rcount, rlist, rbufv, rbufi);
    rescue2b_k<<<64,           256, 0, stream>>>(rcount, rlist, rbufv, rbufi, idxb, counts);
  } else {
    rescue_k<<<1024,           256, 0, stream>>>(z, cb, zin, ein, rcount, rlist, idxb, counts);
  }
  pass2r <<<dim3(32, 32),     256, 0, stream>>>(znh, enh, lse, Ppart);
  k3     <<<NTOK * DDIM / 4 / 256, 256, 0, stream>>>(z, cb, idxb, out, cpart);
  reduceP<<<KCB / 256,        256, 0, stream>>>(Ppart, Psum, 32);
  finalk <<<1,                256, 0, stream>>>(counts, Psum, pema, cpart, out);
}